// Round 6
// baseline (9809.332 us; speedup 1.0000x reference)
//
#include <hip/hip_runtime.h>

#define HD 1024
#define BB 64
#define TT 256
#define VV 128
#define NSTEPS (TT + 3)
#define KSTR 1056                 // padded k-stride for h buffers (bf16 elems)
#define HS (BB * KSTR)            // one h slot, elems
#define GXS (4 * HD * BB)         // one gx1 slot, floats
#define NBLKW 388                 // worker blocks (no master)
#define CHUNK 32768               // ushort elems per block weight chunk (64 KB)
#define LDS_BYTES (65536 + 8192)

typedef __attribute__((ext_vector_type(8))) short bf16x8;
typedef __attribute__((ext_vector_type(4))) float f32x4;

#define MFMA16(a, b, c) __builtin_amdgcn_mfma_f32_16x16x32_bf16((a), (b), (c), 0, 0, 0)

__device__ __forceinline__ unsigned short f2bf(float f) {
  union { float f; unsigned u; } v; v.f = f;
  unsigned r = v.u + 0x7fffu + ((v.u >> 16) & 1u);
  return (unsigned short)(r >> 16);
}
__device__ __forceinline__ float bf2f(unsigned short h) {
  union { unsigned u; float f; } v; v.u = ((unsigned)h) << 16; return v.f;
}
__device__ __forceinline__ float sigf(float x) { return 1.0f / (1.0f + __expf(-x)); }
__device__ __forceinline__ float tanh_f(float x) { return 1.0f - 2.0f / (__expf(2.0f * x) + 1.0f); }

// ---------------- init: transposes, hi/lo bf16 initial states, barrier zero ---
__global__ __launch_bounds__(256) void init_misc(
    const int* __restrict__ x, const float* __restrict__ emb,
    const float* __restrict__ h0in, const float* __restrict__ c0in,
    int* __restrict__ xT, float* __restrict__ embT,
    unsigned short* __restrict__ h0bh, unsigned short* __restrict__ h0bl,
    unsigned short* __restrict__ h1bh, unsigned short* __restrict__ h1bl,
    float* __restrict__ c0, float* __restrict__ c1,
    int* __restrict__ bar)
{
  int tid = blockIdx.x * blockDim.x + threadIdx.x;
  int stride = gridDim.x * blockDim.x;
  const int nXT = TT * BB, nE = VV * HD, nS = HD * BB, nB = 8192;
  const int total = nXT + nE + 4 * nS + nB;
  for (int i = tid; i < total; i += stride) {
    int j = i;
    if (j < nXT) { xT[j] = x[(j & 63) * TT + (j >> 6)]; continue; }       // xT[t][b]
    j -= nXT;
    if (j < nE) { embT[j] = emb[(j & 127) * HD + (j >> 7)]; continue; }   // embT[k][v]
    j -= nE;
    if (j < nS) { int b = j >> 10, n = j & 1023;
      float v = h0in[b * HD + n];
      unsigned short hi = f2bf(v);
      h0bh[HS + b * KSTR + n] = hi;
      h0bl[HS + b * KSTR + n] = f2bf(v - bf2f(hi));
      continue; }                                                          // slot 1
    j -= nS;
    if (j < nS) { int b = j >> 10, n = j & 1023;
      float v = h0in[nS + b * HD + n];
      unsigned short hi = f2bf(v);
      h1bh[HS + b * KSTR + n] = hi;
      h1bl[HS + b * KSTR + n] = f2bf(v - bf2f(hi));
      continue; }
    j -= nS;
    if (j < nS) { int n = j >> 6, b = j & 63;
      c0[n * BB + b] = c0in[b * HD + n]; continue; }
    j -= nS;
    if (j < nS) { int n = j >> 6, b = j & 63;
      c1[n * BB + b] = c0in[nS + b * HD + n]; continue; }
    j -= nS;
    bar[j] = 0;
  }
}

// ---------------- emb_proj = emb @ W_ih0^T + b0, stored [row(4096)][v] fp32 ----
__global__ __launch_bounds__(256) void embproj_kernel(
    const float* __restrict__ Wih0, const float* __restrict__ b0,
    const float* __restrict__ embT, float* __restrict__ embprojT)
{
  const int lane = threadIdx.x & 63;
  const int wave = (blockIdx.x * blockDim.x + threadIdx.x) >> 6;  // 0..1023
  const int n0 = __builtin_amdgcn_readfirstlane(wave * 4);
  const float* __restrict__ r0 = Wih0 + (size_t)n0 * HD;
  const float* __restrict__ r1 = r0 + HD;
  const float* __restrict__ r2 = r1 + HD;
  const float* __restrict__ r3 = r2 + HD;
  float a00=0,a01=0,a10=0,a11=0,a20=0,a21=0,a30=0,a31=0;
  #pragma unroll 4
  for (int k = 0; k < HD; ++k) {
    float e0 = embT[k * VV + lane];
    float e1 = embT[k * VV + 64 + lane];
    float w0 = r0[k], w1 = r1[k], w2 = r2[k], w3 = r3[k];
    a00 = fmaf(e0, w0, a00); a01 = fmaf(e1, w0, a01);
    a10 = fmaf(e0, w1, a10); a11 = fmaf(e1, w1, a11);
    a20 = fmaf(e0, w2, a20); a21 = fmaf(e1, w2, a21);
    a30 = fmaf(e0, w3, a30); a31 = fmaf(e1, w3, a31);
  }
  float bb0 = b0[n0], bb1 = b0[n0+1], bb2 = b0[n0+2], bb3 = b0[n0+3];
  embprojT[(n0+0)*VV + lane]      = a00 + bb0;
  embprojT[(n0+0)*VV + 64 + lane] = a01 + bb0;
  embprojT[(n0+1)*VV + lane]      = a10 + bb1;
  embprojT[(n0+1)*VV + 64 + lane] = a11 + bb1;
  embprojT[(n0+2)*VV + lane]      = a20 + bb2;
  embprojT[(n0+2)*VV + 64 + lane] = a21 + bb2;
  embprojT[(n0+3)*VV + lane]      = a30 + bb3;
  embprojT[(n0+3)*VV + 64 + lane] = a31 + bb3;
}

// ---------------- weight swizzle into per-block MFMA A-frag chunks --------
// chunk[blk][mt][kt][lane][j]  (j=0..7 bf16) ; A[m=lane&15][k=(lane>>4)*8+j]
// hi = bf16(w), lo = bf16(w - hi)
__global__ __launch_bounds__(256) void swizzle_kernel(
    const float* __restrict__ Whh0, const float* __restrict__ Wih1,
    const float* __restrict__ Whh1, const float* __restrict__ fcW,
    unsigned short* __restrict__ wzh, unsigned short* __restrict__ wzl)
{
  int W = (blockIdx.x * blockDim.x + threadIdx.x) >> 6;  // wave id 0..24831
  int lane = threadIdx.x & 63;
  int blk = W >> 6, rem = W & 63;
  int mt = rem >> 5, kt = rem & 31;
  int m = lane & 15, q = lane >> 4;
  int rho = mt * 16 + m;
  const float* src; int srow;
  if (blk < 128)      { src = Whh0; srow = (rho >> 3) * HD + blk * 8 + (rho & 7); }
  else if (blk < 256) { src = Wih1; srow = (blk - 128) * 32 + rho; }
  else if (blk < 384) { src = Whh1; srow = (rho >> 3) * HD + (blk - 256) * 8 + (rho & 7); }
  else                { src = fcW;  srow = (blk - 384) * 32 + rho; }
  int k0 = kt * 32 + q * 8;
  const float* sp = src + (size_t)srow * HD + k0;
  uint4 ohi, olo;
  unsigned short* ph = (unsigned short*)&ohi;
  unsigned short* pl = (unsigned short*)&olo;
  #pragma unroll
  for (int j = 0; j < 8; ++j) {
    float wv = sp[j];
    unsigned short hi = f2bf(wv);
    ph[j] = hi;
    pl[j] = f2bf(wv - bf2f(hi));
  }
  size_t off = (size_t)blk * CHUNK + ((size_t)(mt * 32 + kt) * 64 + lane) * 8;
  *(uint4*)(wzh + off) = ohi;
  *(uint4*)(wzl + off) = olo;
}

// ---------------- persistent pipelined MFMA scan (3-term split precision) ----
// Whi in LDS; Wlo A-frags in VGPRs; all-to-all flag barrier (no master, no RMW).
__global__ __launch_bounds__(128, 2) void scan_kernel(
    const unsigned short* __restrict__ wzh,
    const unsigned short* __restrict__ wzl,
    const float* __restrict__ embprojT,
    const int* __restrict__ xT,
    unsigned short* __restrict__ h0bh, unsigned short* __restrict__ h0bl,
    unsigned short* __restrict__ h1bh, unsigned short* __restrict__ h1bl,
    float* __restrict__ c0,
    float* __restrict__ c1,
    float* __restrict__ gx1,
    const float* __restrict__ b1v,
    const float* __restrict__ fcb,
    float* __restrict__ out,
    int* __restrict__ bar)
{
  extern __shared__ char smem[];
  const bf16x8* wfrag = (const bf16x8*)smem;       // 4096 frags = 64 KB (hi)
  float* red = (float*)(smem + 65536);             // 2048 floats = 8 KB

  const int tid = threadIdx.x, lane = tid & 63, w = tid >> 6;
  const int blk = blockIdx.x;
  const int kt0 = w * 16;

  // one-time: block's hi weight chunk -> LDS
  {
    const uint4* srcp = (const uint4*)(wzh + (size_t)blk * CHUNK);
    uint4* dst = (uint4*)smem;
    for (int i = tid; i < 4096; i += 128) dst[i] = srcp[i];
  }
  // one-time: wave's lo A-frags -> VGPRs (same indices round 4 loaded per step)
  bf16x8 lo0[16], lo1[16];
  {
    const unsigned short* wlo = wzl + (size_t)blk * CHUNK;
    #pragma unroll
    for (int kk = 0; kk < 16; ++kk) {
      lo0[kk] = *(const bf16x8*)(wlo + ((size_t)(0 * 32 + kt0 + kk) * 64 + lane) * 8);
      lo1[kk] = *(const bf16x8*)(wlo + ((size_t)(1 * 32 + kt0 + kk) * 64 + lane) * 8);
    }
  }
  __syncthreads();

  int part, n0 = 0, rg0 = 0;
  if (blk < 128)      { part = 0; n0 = blk * 8; }
  else if (blk < 256) { part = 1; rg0 = (blk - 128) * 32; }
  else if (blk < 384) { part = 2; n0 = (blk - 256) * 8; }
  else                { part = 3; rg0 = (blk - 384) * 32; }

  // per-nt gather offsets into h buffers (elems)
  int goff0 = (0 * 16 + (lane & 15)) * KSTR + (lane >> 4) * 8;
  int goff1 = (1 * 16 + (lane & 15)) * KSTR + (lane >> 4) * 8;
  int goff2 = (2 * 16 + (lane & 15)) * KSTR + (lane >> 4) * 8;
  int goff3 = (3 * 16 + (lane & 15)) * KSTR + (lane >> 4) * 8;

  for (int s = 0; s < NSTEPS; ++s) {
    bool active = (part == 0) ? (s < TT)
                : (part == 1) ? (s >= 1 && s <= TT)
                : (part == 2) ? (s >= 2 && s <= TT + 1)
                :               (s >= 3);
    if (active) {
      const int ps = (s + 1) & 1, cs2 = s & 1;
      const bool l0src = (part == 0 || part == 1);
      const unsigned short* hsrcH = (l0src ? h0bh : h1bh) + ps * HS;
      const unsigned short* hsrcL = (l0src ? h0bl : h1bl) + ps * HS;
      const unsigned short* hbh0 = hsrcH + goff0;
      const unsigned short* hbh1 = hsrcH + goff1;
      const unsigned short* hbh2 = hsrcH + goff2;
      const unsigned short* hbh3 = hsrcH + goff3;
      const unsigned short* hbl0 = hsrcL + goff0;
      const unsigned short* hbl1 = hsrcL + goff1;
      const unsigned short* hbl2 = hsrcL + goff2;
      const unsigned short* hbl3 = hsrcL + goff3;

      f32x4 acc[2][4];
      #pragma unroll
      for (int i = 0; i < 2; ++i)
        #pragma unroll
        for (int j = 0; j < 4; ++j) acc[i][j] = (f32x4){0.f, 0.f, 0.f, 0.f};

      #pragma unroll 4
      for (int kk = 0; kk < 16; ++kk) {
        int kt = kt0 + kk;
        bf16x8 a0  = wfrag[kt * 64 + lane];
        bf16x8 a1  = wfrag[(32 + kt) * 64 + lane];
        bf16x8 b0  = *(const bf16x8*)(hbh0 + kt * 32);
        bf16x8 b1  = *(const bf16x8*)(hbh1 + kt * 32);
        bf16x8 b2  = *(const bf16x8*)(hbh2 + kt * 32);
        bf16x8 b3  = *(const bf16x8*)(hbh3 + kt * 32);
        bf16x8 c0f = *(const bf16x8*)(hbl0 + kt * 32);
        bf16x8 c1f = *(const bf16x8*)(hbl1 + kt * 32);
        bf16x8 c2f = *(const bf16x8*)(hbl2 + kt * 32);
        bf16x8 c3f = *(const bf16x8*)(hbl3 + kt * 32);
        // hi*hi
        acc[0][0] = MFMA16(a0, b0, acc[0][0]);
        acc[0][1] = MFMA16(a0, b1, acc[0][1]);
        acc[0][2] = MFMA16(a0, b2, acc[0][2]);
        acc[0][3] = MFMA16(a0, b3, acc[0][3]);
        acc[1][0] = MFMA16(a1, b0, acc[1][0]);
        acc[1][1] = MFMA16(a1, b1, acc[1][1]);
        acc[1][2] = MFMA16(a1, b2, acc[1][2]);
        acc[1][3] = MFMA16(a1, b3, acc[1][3]);
        // hi*lo (h-lo)
        acc[0][0] = MFMA16(a0, c0f, acc[0][0]);
        acc[0][1] = MFMA16(a0, c1f, acc[0][1]);
        acc[0][2] = MFMA16(a0, c2f, acc[0][2]);
        acc[0][3] = MFMA16(a0, c3f, acc[0][3]);
        acc[1][0] = MFMA16(a1, c0f, acc[1][0]);
        acc[1][1] = MFMA16(a1, c1f, acc[1][1]);
        acc[1][2] = MFMA16(a1, c2f, acc[1][2]);
        acc[1][3] = MFMA16(a1, c3f, acc[1][3]);
        // lo*hi (w-lo from VGPRs)
        acc[0][0] = MFMA16(lo0[kk], b0, acc[0][0]);
        acc[0][1] = MFMA16(lo0[kk], b1, acc[0][1]);
        acc[0][2] = MFMA16(lo0[kk], b2, acc[0][2]);
        acc[0][3] = MFMA16(lo0[kk], b3, acc[0][3]);
        acc[1][0] = MFMA16(lo1[kk], b0, acc[1][0]);
        acc[1][1] = MFMA16(lo1[kk], b1, acc[1][1]);
        acc[1][2] = MFMA16(lo1[kk], b2, acc[1][2]);
        acc[1][3] = MFMA16(lo1[kk], b3, acc[1][3]);
      }

      // epilogue: 2 rounds (b 0..31, 32..63); K-partials reduced in LDS
      #pragma unroll
      for (int ro = 0; ro < 2; ++ro) {
        #pragma unroll
        for (int mt = 0; mt < 2; ++mt)
          #pragma unroll
          for (int ntl = 0; ntl < 2; ++ntl) {
            f32x4 v = acc[mt][ro * 2 + ntl];
            int base = w * 1024 + (mt * 16 + (lane >> 4) * 4) * 32 + ntl * 16 + (lane & 15);
            red[base + 0 * 32] = v[0];
            red[base + 1 * 32] = v[1];
            red[base + 2 * 32] = v[2];
            red[base + 3 * 32] = v[3];
          }
        __syncthreads();

        if (part == 0 || part == 2) {
          int nl = tid >> 4, bp = (tid & 15) * 2;
          int b = ro * 32 + bp;
          int n = n0 + nl;
          float2 p0, p1, p2, p3;
          {
            int ix = (0 * 8 + nl) * 32 + bp;
            float2 u0 = *(const float2*)&red[ix], u1 = *(const float2*)&red[1024 + ix];
            p0 = make_float2(u0.x + u1.x, u0.y + u1.y);
            ix = (1 * 8 + nl) * 32 + bp;
            u0 = *(const float2*)&red[ix]; u1 = *(const float2*)&red[1024 + ix];
            p1 = make_float2(u0.x + u1.x, u0.y + u1.y);
            ix = (2 * 8 + nl) * 32 + bp;
            u0 = *(const float2*)&red[ix]; u1 = *(const float2*)&red[1024 + ix];
            p2 = make_float2(u0.x + u1.x, u0.y + u1.y);
            ix = (3 * 8 + nl) * 32 + bp;
            u0 = *(const float2*)&red[ix]; u1 = *(const float2*)&red[1024 + ix];
            p3 = make_float2(u0.x + u1.x, u0.y + u1.y);
          }
          float pi0, pf0, pg0, po0, pi1, pf1, pg1, po1;
          if (part == 0) {
            int xv0 = xT[s * BB + b], xv1 = xT[s * BB + b + 1];
            pi0 = p0.x + embprojT[(0 * HD + n) * VV + xv0];
            pf0 = p1.x + embprojT[(1 * HD + n) * VV + xv0];
            pg0 = p2.x + embprojT[(2 * HD + n) * VV + xv0];
            po0 = p3.x + embprojT[(3 * HD + n) * VV + xv0];
            pi1 = p0.y + embprojT[(0 * HD + n) * VV + xv1];
            pf1 = p1.y + embprojT[(1 * HD + n) * VV + xv1];
            pg1 = p2.y + embprojT[(2 * HD + n) * VV + xv1];
            po1 = p3.y + embprojT[(3 * HD + n) * VV + xv1];
          } else {
            const float* gx = gx1 + ps * GXS;
            float2 q0 = *(const float2*)&gx[(0 * HD + n) * BB + b];
            float2 q1 = *(const float2*)&gx[(1 * HD + n) * BB + b];
            float2 q2 = *(const float2*)&gx[(2 * HD + n) * BB + b];
            float2 q3 = *(const float2*)&gx[(3 * HD + n) * BB + b];
            pi0 = p0.x + q0.x; pf0 = p1.x + q1.x; pg0 = p2.x + q2.x; po0 = p3.x + q3.x;
            pi1 = p0.y + q0.y; pf1 = p1.y + q1.y; pg1 = p2.y + q2.y; po1 = p3.y + q3.y;
          }
          float* cc = (part == 0) ? c0 : c1;
          float2 cold = *(const float2*)&cc[n * BB + b];
          float cn0 = sigf(pf0) * cold.x + sigf(pi0) * tanh_f(pg0);
          float cn1 = sigf(pf1) * cold.y + sigf(pi1) * tanh_f(pg1);
          *(float2*)&cc[n * BB + b] = make_float2(cn0, cn1);
          float hv0 = sigf(po0) * tanh_f(cn0);
          float hv1 = sigf(po1) * tanh_f(cn1);
          unsigned short* hwh = ((part == 0) ? h0bh : h1bh) + cs2 * HS;
          unsigned short* hwl = ((part == 0) ? h0bl : h1bl) + cs2 * HS;
          unsigned short e0 = f2bf(hv0);
          unsigned short e1 = f2bf(hv1);
          hwh[b * KSTR + n]       = e0;
          hwh[(b + 1) * KSTR + n] = e1;
          hwl[b * KSTR + n]       = f2bf(hv0 - bf2f(e0));
          hwl[(b + 1) * KSTR + n] = f2bf(hv1 - bf2f(e1));
        } else {
          int rb = (tid >> 4) * 4, bp = (tid & 15) * 2;
          int b = ro * 32 + bp;
          #pragma unroll
          for (int rr = 0; rr < 4; ++rr) {
            int rho = rb + rr, ix = rho * 32 + bp;
            float2 u0 = *(const float2*)&red[ix], u1 = *(const float2*)&red[1024 + ix];
            if (part == 1) {
              float bias = b1v[rg0 + rho];
              float2 sm = make_float2(u0.x + u1.x + bias, u0.y + u1.y + bias);
              *(float2*)&gx1[cs2 * GXS + (rg0 + rho) * BB + b] = sm;
            } else {
              float bias = fcb[rg0 + rho];
              int t = s - 3;
              out[(size_t)b * (TT * VV) + t * VV + rg0 + rho]       = u0.x + u1.x + bias;
              out[(size_t)(b + 1) * (TT * VV) + t * VV + rg0 + rho] = u0.y + u1.y + bias;
            }
          }
        }
        __syncthreads();
      }
    }

    // ---------- all-to-all contention-free barrier ----------
    __syncthreads();
    if (tid == 0) {
      __builtin_amdgcn_fence(__ATOMIC_RELEASE, "agent");   // drain + wb L2
      __hip_atomic_store(&bar[blk * 16], s + 1, __ATOMIC_RELAXED, __HIP_MEMORY_SCOPE_AGENT);
    }
    while (__hip_atomic_load(&bar[tid * 16], __ATOMIC_RELAXED, __HIP_MEMORY_SCOPE_AGENT) < s + 1)
      __builtin_amdgcn_s_sleep(1);
    while (__hip_atomic_load(&bar[(128 + tid) * 16], __ATOMIC_RELAXED, __HIP_MEMORY_SCOPE_AGENT) < s + 1)
      __builtin_amdgcn_s_sleep(1);
    if (256 + tid < NBLKW)
      while (__hip_atomic_load(&bar[(256 + tid) * 16], __ATOMIC_RELAXED, __HIP_MEMORY_SCOPE_AGENT) < s + 1)
        __builtin_amdgcn_s_sleep(1);
    __syncthreads();
    __builtin_amdgcn_fence(__ATOMIC_ACQUIRE, "agent");     // inv stale lines
  }
}

extern "C" void kernel_launch(void* const* d_in, const int* in_sizes, int n_in,
                              void* d_out, int out_size, void* d_ws, size_t ws_size,
                              hipStream_t stream) {
  (void)in_sizes; (void)n_in; (void)out_size; (void)ws_size;
  const int*   x    = (const int*)d_in[0];
  const float* emb  = (const float*)d_in[1];
  const float* Wih0 = (const float*)d_in[2];
  const float* Whh0 = (const float*)d_in[3];
  const float* b0   = (const float*)d_in[4];
  const float* Wih1 = (const float*)d_in[5];
  const float* Whh1 = (const float*)d_in[6];
  const float* b1   = (const float*)d_in[7];
  const float* fcW  = (const float*)d_in[8];
  const float* fcb  = (const float*)d_in[9];
  const float* h0in = (const float*)d_in[10];
  const float* c0in = (const float*)d_in[11];
  float* out = (float*)d_out;
  char* ws = (char*)d_ws;

  // workspace layout (bytes, 16B aligned); total ~57.3 MB
  unsigned short* wzh      = (unsigned short*)(ws + 0);           // 25,427,968
  unsigned short* wzl      = (unsigned short*)(ws + 25427968);    // 25,427,968
  float*          embprojT = (float*)(ws + 50855936);             //  2,097,152
  float*          embT     = (float*)(ws + 52953088);             //    524,288
  unsigned short* h0bh     = (unsigned short*)(ws + 53477376);    //    270,336
  unsigned short* h0bl     = (unsigned short*)(ws + 53747712);    //    270,336
  unsigned short* h1bh     = (unsigned short*)(ws + 54018048);    //    270,336
  unsigned short* h1bl     = (unsigned short*)(ws + 54288384);    //    270,336
  float*          c0       = (float*)(ws + 54558720);             //    262,144
  float*          c1       = (float*)(ws + 54820864);             //    262,144
  float*          gx1      = (float*)(ws + 55083008);             //  2,097,152
  int*            xT       = (int*)(ws + 57180160);               //     65,536
  int*            bar      = (int*)(ws + 57245696);               //     32,768

  hipLaunchKernelGGL(init_misc, dim3(512), dim3(256), 0, stream,
                     x, emb, h0in, c0in, xT, embT, h0bh, h0bl, h1bh, h1bl, c0, c1, bar);
  hipLaunchKernelGGL(swizzle_kernel, dim3(6208), dim3(256), 0, stream,
                     Whh0, Wih1, Whh1, fcW, wzh, wzl);
  hipLaunchKernelGGL(embproj_kernel, dim3(256), dim3(256), 0, stream,
                     Wih0, b0, embT, embprojT);

  hipFuncSetAttribute((const void*)scan_kernel,
                      hipFuncAttributeMaxDynamicSharedMemorySize, LDS_BYTES);

  void* args[] = {
    (void*)&wzh, (void*)&wzl, (void*)&embprojT, (void*)&xT,
    (void*)&h0bh, (void*)&h0bl, (void*)&h1bh, (void*)&h1bl,
    (void*)&c0, (void*)&c1, (void*)&gx1, (void*)&b1, (void*)&fcb, (void*)&out,
    (void*)&bar
  };
  hipLaunchCooperativeKernel((void*)scan_kernel, dim3(NBLKW), dim3(128),
                             args, LDS_BYTES, stream);
}

// Round 7
// 8909.227 us; speedup vs baseline: 1.1010x; 1.1010x over previous
//
#include <hip/hip_runtime.h>

#define HD 1024
#define BB 64
#define TT 256
#define VV 128
#define NSTEPS (TT + 3)
#define KSTR 1056                 // padded k-stride for h buffers (bf16 elems)
#define HS (BB * KSTR)            // one h slot, elems
#define GXS (4 * HD * BB)         // one gx1 slot, floats
#define NBLKW 388                 // worker blocks
#define GRID (NBLKW + 1)          // + 1 barrier-master block
#define GO_OFF 7936               // int offset of 'go' epoch in bar region
#define CHUNK 32768               // ushort elems per block weight chunk (64 KB)
#define LDS_BYTES (65536 + 8192)

typedef __attribute__((ext_vector_type(8))) short bf16x8;
typedef __attribute__((ext_vector_type(4))) float f32x4;

#define MFMA16(a, b, c) __builtin_amdgcn_mfma_f32_16x16x32_bf16((a), (b), (c), 0, 0, 0)

__device__ __forceinline__ unsigned short f2bf(float f) {
  union { float f; unsigned u; } v; v.f = f;
  unsigned r = v.u + 0x7fffu + ((v.u >> 16) & 1u);
  return (unsigned short)(r >> 16);
}
__device__ __forceinline__ float bf2f(unsigned short h) {
  union { unsigned u; float f; } v; v.u = ((unsigned)h) << 16; return v.f;
}
__device__ __forceinline__ float sigf(float x) { return 1.0f / (1.0f + __expf(-x)); }
__device__ __forceinline__ float tanh_f(float x) { return 1.0f - 2.0f / (__expf(2.0f * x) + 1.0f); }

// ---------------- init: transposes, hi/lo bf16 initial states, barrier zero ---
__global__ __launch_bounds__(256) void init_misc(
    const int* __restrict__ x, const float* __restrict__ emb,
    const float* __restrict__ h0in, const float* __restrict__ c0in,
    int* __restrict__ xT, float* __restrict__ embT,
    unsigned short* __restrict__ h0bh, unsigned short* __restrict__ h0bl,
    unsigned short* __restrict__ h1bh, unsigned short* __restrict__ h1bl,
    float* __restrict__ c0, float* __restrict__ c1,
    int* __restrict__ bar)
{
  int tid = blockIdx.x * blockDim.x + threadIdx.x;
  int stride = gridDim.x * blockDim.x;
  const int nXT = TT * BB, nE = VV * HD, nS = HD * BB, nB = 8192;
  const int total = nXT + nE + 4 * nS + nB;
  for (int i = tid; i < total; i += stride) {
    int j = i;
    if (j < nXT) { xT[j] = x[(j & 63) * TT + (j >> 6)]; continue; }       // xT[t][b]
    j -= nXT;
    if (j < nE) { embT[j] = emb[(j & 127) * HD + (j >> 7)]; continue; }   // embT[k][v]
    j -= nE;
    if (j < nS) { int b = j >> 10, n = j & 1023;
      float v = h0in[b * HD + n];
      unsigned short hi = f2bf(v);
      h0bh[HS + b * KSTR + n] = hi;
      h0bl[HS + b * KSTR + n] = f2bf(v - bf2f(hi));
      continue; }                                                          // slot 1
    j -= nS;
    if (j < nS) { int b = j >> 10, n = j & 1023;
      float v = h0in[nS + b * HD + n];
      unsigned short hi = f2bf(v);
      h1bh[HS + b * KSTR + n] = hi;
      h1bl[HS + b * KSTR + n] = f2bf(v - bf2f(hi));
      continue; }
    j -= nS;
    if (j < nS) { int n = j >> 6, b = j & 63;
      c0[n * BB + b] = c0in[b * HD + n]; continue; }
    j -= nS;
    if (j < nS) { int n = j >> 6, b = j & 63;
      c1[n * BB + b] = c0in[nS + b * HD + n]; continue; }
    j -= nS;
    bar[j] = 0;
  }
}

// ---------------- emb_proj = emb @ W_ih0^T + b0, stored [row(4096)][v] fp32 ----
__global__ __launch_bounds__(256) void embproj_kernel(
    const float* __restrict__ Wih0, const float* __restrict__ b0,
    const float* __restrict__ embT, float* __restrict__ embprojT)
{
  const int lane = threadIdx.x & 63;
  const int wave = (blockIdx.x * blockDim.x + threadIdx.x) >> 6;  // 0..1023
  const int n0 = __builtin_amdgcn_readfirstlane(wave * 4);
  const float* __restrict__ r0 = Wih0 + (size_t)n0 * HD;
  const float* __restrict__ r1 = r0 + HD;
  const float* __restrict__ r2 = r1 + HD;
  const float* __restrict__ r3 = r2 + HD;
  float a00=0,a01=0,a10=0,a11=0,a20=0,a21=0,a30=0,a31=0;
  #pragma unroll 4
  for (int k = 0; k < HD; ++k) {
    float e0 = embT[k * VV + lane];
    float e1 = embT[k * VV + 64 + lane];
    float w0 = r0[k], w1 = r1[k], w2 = r2[k], w3 = r3[k];
    a00 = fmaf(e0, w0, a00); a01 = fmaf(e1, w0, a01);
    a10 = fmaf(e0, w1, a10); a11 = fmaf(e1, w1, a11);
    a20 = fmaf(e0, w2, a20); a21 = fmaf(e1, w2, a21);
    a30 = fmaf(e0, w3, a30); a31 = fmaf(e1, w3, a31);
  }
  float bb0 = b0[n0], bb1 = b0[n0+1], bb2 = b0[n0+2], bb3 = b0[n0+3];
  embprojT[(n0+0)*VV + lane]      = a00 + bb0;
  embprojT[(n0+0)*VV + 64 + lane] = a01 + bb0;
  embprojT[(n0+1)*VV + lane]      = a10 + bb1;
  embprojT[(n0+1)*VV + 64 + lane] = a11 + bb1;
  embprojT[(n0+2)*VV + lane]      = a20 + bb2;
  embprojT[(n0+2)*VV + 64 + lane] = a21 + bb2;
  embprojT[(n0+3)*VV + lane]      = a30 + bb3;
  embprojT[(n0+3)*VV + 64 + lane] = a31 + bb3;
}

// ---------------- weight swizzle into per-block MFMA A-frag chunks --------
// chunk[blk][mt][kt][lane][j]  (j=0..7 bf16) ; A[m=lane&15][k=(lane>>4)*8+j]
// hi = bf16(w), lo = bf16(w - hi)
__global__ __launch_bounds__(256) void swizzle_kernel(
    const float* __restrict__ Whh0, const float* __restrict__ Wih1,
    const float* __restrict__ Whh1, const float* __restrict__ fcW,
    unsigned short* __restrict__ wzh, unsigned short* __restrict__ wzl)
{
  int W = (blockIdx.x * blockDim.x + threadIdx.x) >> 6;  // wave id 0..24831
  int lane = threadIdx.x & 63;
  int blk = W >> 6, rem = W & 63;
  int mt = rem >> 5, kt = rem & 31;
  int m = lane & 15, q = lane >> 4;
  int rho = mt * 16 + m;
  const float* src; int srow;
  if (blk < 128)      { src = Whh0; srow = (rho >> 3) * HD + blk * 8 + (rho & 7); }
  else if (blk < 256) { src = Wih1; srow = (blk - 128) * 32 + rho; }
  else if (blk < 384) { src = Whh1; srow = (rho >> 3) * HD + (blk - 256) * 8 + (rho & 7); }
  else                { src = fcW;  srow = (blk - 384) * 32 + rho; }
  int k0 = kt * 32 + q * 8;
  const float* sp = src + (size_t)srow * HD + k0;
  uint4 ohi, olo;
  unsigned short* ph = (unsigned short*)&ohi;
  unsigned short* pl = (unsigned short*)&olo;
  #pragma unroll
  for (int j = 0; j < 8; ++j) {
    float wv = sp[j];
    unsigned short hi = f2bf(wv);
    ph[j] = hi;
    pl[j] = f2bf(wv - bf2f(hi));
  }
  size_t off = (size_t)blk * CHUNK + ((size_t)(mt * 32 + kt) * 64 + lane) * 8;
  *(uint4*)(wzh + off) = ohi;
  *(uint4*)(wzl + off) = olo;
}

// ---------------- persistent pipelined MFMA scan (3-term split precision) ----
// Whi in LDS; Wlo in VGPRs (fully-unrolled K-loop -> static indices);
// c-state in VGPRs; master-block flag barrier (round-4 verified).
__global__ __launch_bounds__(128, 2) void scan_kernel(
    const unsigned short* __restrict__ wzh,
    const unsigned short* __restrict__ wzl,
    const float* __restrict__ embprojT,
    const int* __restrict__ xT,
    unsigned short* __restrict__ h0bh, unsigned short* __restrict__ h0bl,
    unsigned short* __restrict__ h1bh, unsigned short* __restrict__ h1bl,
    float* __restrict__ c0,
    float* __restrict__ c1,
    float* __restrict__ gx1,
    const float* __restrict__ b1v,
    const float* __restrict__ fcb,
    float* __restrict__ out,
    int* __restrict__ bar)
{
  extern __shared__ char smem[];
  const bf16x8* wfrag = (const bf16x8*)smem;       // 4096 frags = 64 KB (hi)
  float* red = (float*)(smem + 65536);             // 2048 floats = 8 KB

  const int tid = threadIdx.x, lane = tid & 63, w = tid >> 6;
  const int blk = blockIdx.x;

  // ---------- barrier master block ----------
  if (blk == NBLKW) {
    const int f0 = tid, f1 = tid + 128, f2 = tid + 256;
    for (int s = 1; s <= NSTEPS; ++s) {
      while (__hip_atomic_load(&bar[f0 * 16], __ATOMIC_RELAXED, __HIP_MEMORY_SCOPE_AGENT) < s)
        __builtin_amdgcn_s_sleep(1);
      while (__hip_atomic_load(&bar[f1 * 16], __ATOMIC_RELAXED, __HIP_MEMORY_SCOPE_AGENT) < s)
        __builtin_amdgcn_s_sleep(1);
      while (__hip_atomic_load(&bar[f2 * 16], __ATOMIC_RELAXED, __HIP_MEMORY_SCOPE_AGENT) < s)
        __builtin_amdgcn_s_sleep(1);
      if (tid < 4)
        while (__hip_atomic_load(&bar[(384 + tid) * 16], __ATOMIC_RELAXED, __HIP_MEMORY_SCOPE_AGENT) < s)
          __builtin_amdgcn_s_sleep(1);
      __syncthreads();
      if (tid == 0) {
        __builtin_amdgcn_fence(__ATOMIC_ACQUIRE, "agent");
        __hip_atomic_store(&bar[GO_OFF], s, __ATOMIC_RELAXED, __HIP_MEMORY_SCOPE_AGENT);
      }
    }
    return;
  }

  const int kt0 = w * 16;

  // one-time: block's hi weight chunk -> LDS
  {
    const uint4* srcp = (const uint4*)(wzh + (size_t)blk * CHUNK);
    uint4* dst = (uint4*)smem;
    for (int i = tid; i < 4096; i += 128) dst[i] = srcp[i];
  }
  // one-time: wave's lo A-frags -> VGPRs (K-loop below is FULLY unrolled,
  // so lo0/lo1 indices are static -> true registers, not scratch)
  bf16x8 lo0[16], lo1[16];
  {
    const unsigned short* wlo = wzl + (size_t)blk * CHUNK;
    #pragma unroll
    for (int kk = 0; kk < 16; ++kk) {
      lo0[kk] = *(const bf16x8*)(wlo + ((size_t)(0 * 32 + kt0 + kk) * 64 + lane) * 8);
      lo1[kk] = *(const bf16x8*)(wlo + ((size_t)(1 * 32 + kt0 + kk) * 64 + lane) * 8);
    }
  }
  __syncthreads();

  int part, n0 = 0, rg0 = 0;
  if (blk < 128)      { part = 0; n0 = blk * 8; }
  else if (blk < 256) { part = 1; rg0 = (blk - 128) * 32; }
  else if (blk < 384) { part = 2; n0 = (blk - 256) * 8; }
  else                { part = 3; rg0 = (blk - 384) * 32; }

  // c-state in VGPRs: thread owns (n = n0 + (tid>>4), b = ro*32 + (tid&15)*2 + {0,1})
  float creg[2][2];
  if (part == 0 || part == 2) {
    const float* cc = (part == 0) ? c0 : c1;
    int nl = tid >> 4, bp = (tid & 15) * 2;
    int n = n0 + nl;
    float2 v0 = *(const float2*)&cc[n * BB + bp];
    float2 v1 = *(const float2*)&cc[n * BB + 32 + bp];
    creg[0][0] = v0.x; creg[0][1] = v0.y;
    creg[1][0] = v1.x; creg[1][1] = v1.y;
  }

  // per-nt gather offsets into h buffers (elems)
  int goff0 = (0 * 16 + (lane & 15)) * KSTR + (lane >> 4) * 8;
  int goff1 = (1 * 16 + (lane & 15)) * KSTR + (lane >> 4) * 8;
  int goff2 = (2 * 16 + (lane & 15)) * KSTR + (lane >> 4) * 8;
  int goff3 = (3 * 16 + (lane & 15)) * KSTR + (lane >> 4) * 8;

  for (int s = 0; s < NSTEPS; ++s) {
    bool active = (part == 0) ? (s < TT)
                : (part == 1) ? (s >= 1 && s <= TT)
                : (part == 2) ? (s >= 2 && s <= TT + 1)
                :               (s >= 3);
    if (active) {
      const int ps = (s + 1) & 1, cs2 = s & 1;
      const bool l0src = (part == 0 || part == 1);
      const unsigned short* hsrcH = (l0src ? h0bh : h1bh) + ps * HS;
      const unsigned short* hsrcL = (l0src ? h0bl : h1bl) + ps * HS;
      const unsigned short* hbh0 = hsrcH + goff0;
      const unsigned short* hbh1 = hsrcH + goff1;
      const unsigned short* hbh2 = hsrcH + goff2;
      const unsigned short* hbh3 = hsrcH + goff3;
      const unsigned short* hbl0 = hsrcL + goff0;
      const unsigned short* hbl1 = hsrcL + goff1;
      const unsigned short* hbl2 = hsrcL + goff2;
      const unsigned short* hbl3 = hsrcL + goff3;

      f32x4 acc[2][4];
      #pragma unroll
      for (int i = 0; i < 2; ++i)
        #pragma unroll
        for (int j = 0; j < 4; ++j) acc[i][j] = (f32x4){0.f, 0.f, 0.f, 0.f};

      #pragma unroll
      for (int kk = 0; kk < 16; ++kk) {
        int kt = kt0 + kk;
        bf16x8 a0  = wfrag[kt * 64 + lane];
        bf16x8 a1  = wfrag[(32 + kt) * 64 + lane];
        bf16x8 b0  = *(const bf16x8*)(hbh0 + kt * 32);
        bf16x8 b1  = *(const bf16x8*)(hbh1 + kt * 32);
        bf16x8 b2  = *(const bf16x8*)(hbh2 + kt * 32);
        bf16x8 b3  = *(const bf16x8*)(hbh3 + kt * 32);
        bf16x8 c0f = *(const bf16x8*)(hbl0 + kt * 32);
        bf16x8 c1f = *(const bf16x8*)(hbl1 + kt * 32);
        bf16x8 c2f = *(const bf16x8*)(hbl2 + kt * 32);
        bf16x8 c3f = *(const bf16x8*)(hbl3 + kt * 32);
        // hi*hi
        acc[0][0] = MFMA16(a0, b0, acc[0][0]);
        acc[0][1] = MFMA16(a0, b1, acc[0][1]);
        acc[0][2] = MFMA16(a0, b2, acc[0][2]);
        acc[0][3] = MFMA16(a0, b3, acc[0][3]);
        acc[1][0] = MFMA16(a1, b0, acc[1][0]);
        acc[1][1] = MFMA16(a1, b1, acc[1][1]);
        acc[1][2] = MFMA16(a1, b2, acc[1][2]);
        acc[1][3] = MFMA16(a1, b3, acc[1][3]);
        // hi*lo (h-lo)
        acc[0][0] = MFMA16(a0, c0f, acc[0][0]);
        acc[0][1] = MFMA16(a0, c1f, acc[0][1]);
        acc[0][2] = MFMA16(a0, c2f, acc[0][2]);
        acc[0][3] = MFMA16(a0, c3f, acc[0][3]);
        acc[1][0] = MFMA16(a1, c0f, acc[1][0]);
        acc[1][1] = MFMA16(a1, c1f, acc[1][1]);
        acc[1][2] = MFMA16(a1, c2f, acc[1][2]);
        acc[1][3] = MFMA16(a1, c3f, acc[1][3]);
        // lo*hi (w-lo from VGPRs, static index)
        acc[0][0] = MFMA16(lo0[kk], b0, acc[0][0]);
        acc[0][1] = MFMA16(lo0[kk], b1, acc[0][1]);
        acc[0][2] = MFMA16(lo0[kk], b2, acc[0][2]);
        acc[0][3] = MFMA16(lo0[kk], b3, acc[0][3]);
        acc[1][0] = MFMA16(lo1[kk], b0, acc[1][0]);
        acc[1][1] = MFMA16(lo1[kk], b1, acc[1][1]);
        acc[1][2] = MFMA16(lo1[kk], b2, acc[1][2]);
        acc[1][3] = MFMA16(lo1[kk], b3, acc[1][3]);
      }

      // epilogue: 2 rounds (b 0..31, 32..63); K-partials reduced in LDS
      #pragma unroll
      for (int ro = 0; ro < 2; ++ro) {
        #pragma unroll
        for (int mt = 0; mt < 2; ++mt)
          #pragma unroll
          for (int ntl = 0; ntl < 2; ++ntl) {
            f32x4 v = acc[mt][ro * 2 + ntl];
            int base = w * 1024 + (mt * 16 + (lane >> 4) * 4) * 32 + ntl * 16 + (lane & 15);
            red[base + 0 * 32] = v[0];
            red[base + 1 * 32] = v[1];
            red[base + 2 * 32] = v[2];
            red[base + 3 * 32] = v[3];
          }
        __syncthreads();

        if (part == 0 || part == 2) {
          int nl = tid >> 4, bp = (tid & 15) * 2;
          int b = ro * 32 + bp;
          int n = n0 + nl;
          float2 p0, p1, p2, p3;
          {
            int ix = (0 * 8 + nl) * 32 + bp;
            float2 u0 = *(const float2*)&red[ix], u1 = *(const float2*)&red[1024 + ix];
            p0 = make_float2(u0.x + u1.x, u0.y + u1.y);
            ix = (1 * 8 + nl) * 32 + bp;
            u0 = *(const float2*)&red[ix]; u1 = *(const float2*)&red[1024 + ix];
            p1 = make_float2(u0.x + u1.x, u0.y + u1.y);
            ix = (2 * 8 + nl) * 32 + bp;
            u0 = *(const float2*)&red[ix]; u1 = *(const float2*)&red[1024 + ix];
            p2 = make_float2(u0.x + u1.x, u0.y + u1.y);
            ix = (3 * 8 + nl) * 32 + bp;
            u0 = *(const float2*)&red[ix]; u1 = *(const float2*)&red[1024 + ix];
            p3 = make_float2(u0.x + u1.x, u0.y + u1.y);
          }
          float pi0, pf0, pg0, po0, pi1, pf1, pg1, po1;
          if (part == 0) {
            int xv0 = xT[s * BB + b], xv1 = xT[s * BB + b + 1];
            pi0 = p0.x + embprojT[(0 * HD + n) * VV + xv0];
            pf0 = p1.x + embprojT[(1 * HD + n) * VV + xv0];
            pg0 = p2.x + embprojT[(2 * HD + n) * VV + xv0];
            po0 = p3.x + embprojT[(3 * HD + n) * VV + xv0];
            pi1 = p0.y + embprojT[(0 * HD + n) * VV + xv1];
            pf1 = p1.y + embprojT[(1 * HD + n) * VV + xv1];
            pg1 = p2.y + embprojT[(2 * HD + n) * VV + xv1];
            po1 = p3.y + embprojT[(3 * HD + n) * VV + xv1];
          } else {
            const float* gx = gx1 + ps * GXS;
            float2 q0 = *(const float2*)&gx[(0 * HD + n) * BB + b];
            float2 q1 = *(const float2*)&gx[(1 * HD + n) * BB + b];
            float2 q2 = *(const float2*)&gx[(2 * HD + n) * BB + b];
            float2 q3 = *(const float2*)&gx[(3 * HD + n) * BB + b];
            pi0 = p0.x + q0.x; pf0 = p1.x + q1.x; pg0 = p2.x + q2.x; po0 = p3.x + q3.x;
            pi1 = p0.y + q0.y; pf1 = p1.y + q1.y; pg1 = p2.y + q2.y; po1 = p3.y + q3.y;
          }
          float cn0 = sigf(pf0) * creg[ro][0] + sigf(pi0) * tanh_f(pg0);
          float cn1 = sigf(pf1) * creg[ro][1] + sigf(pi1) * tanh_f(pg1);
          creg[ro][0] = cn0; creg[ro][1] = cn1;
          float hv0 = sigf(po0) * tanh_f(cn0);
          float hv1 = sigf(po1) * tanh_f(cn1);
          unsigned short* hwh = ((part == 0) ? h0bh : h1bh) + cs2 * HS;
          unsigned short* hwl = ((part == 0) ? h0bl : h1bl) + cs2 * HS;
          unsigned short e0 = f2bf(hv0);
          unsigned short e1 = f2bf(hv1);
          hwh[b * KSTR + n]       = e0;
          hwh[(b + 1) * KSTR + n] = e1;
          hwl[b * KSTR + n]       = f2bf(hv0 - bf2f(e0));
          hwl[(b + 1) * KSTR + n] = f2bf(hv1 - bf2f(e1));
        } else {
          int rb = (tid >> 4) * 4, bp = (tid & 15) * 2;
          int b = ro * 32 + bp;
          #pragma unroll
          for (int rr = 0; rr < 4; ++rr) {
            int rho = rb + rr, ix = rho * 32 + bp;
            float2 u0 = *(const float2*)&red[ix], u1 = *(const float2*)&red[1024 + ix];
            if (part == 1) {
              float bias = b1v[rg0 + rho];
              float2 sm = make_float2(u0.x + u1.x + bias, u0.y + u1.y + bias);
              *(float2*)&gx1[cs2 * GXS + (rg0 + rho) * BB + b] = sm;
            } else {
              float bias = fcb[rg0 + rho];
              int t = s - 3;
              out[(size_t)b * (TT * VV) + t * VV + rg0 + rho]       = u0.x + u1.x + bias;
              out[(size_t)(b + 1) * (TT * VV) + t * VV + rg0 + rho] = u0.y + u1.y + bias;
            }
          }
        }
        __syncthreads();
      }
    }

    // ---------- contention-free master barrier (round-4 verified) ----------
    if (tid == 0) {
      __builtin_amdgcn_fence(__ATOMIC_RELEASE, "agent");   // drain + wb L2
      __hip_atomic_store(&bar[blk * 16], s + 1, __ATOMIC_RELAXED, __HIP_MEMORY_SCOPE_AGENT);
      while (__hip_atomic_load(&bar[GO_OFF], __ATOMIC_RELAXED, __HIP_MEMORY_SCOPE_AGENT) < s + 1)
        __builtin_amdgcn_s_sleep(1);
      __builtin_amdgcn_fence(__ATOMIC_ACQUIRE, "agent");   // inv stale lines (L1/L2 cache-wide)
    }
    __syncthreads();
  }
}

extern "C" void kernel_launch(void* const* d_in, const int* in_sizes, int n_in,
                              void* d_out, int out_size, void* d_ws, size_t ws_size,
                              hipStream_t stream) {
  (void)in_sizes; (void)n_in; (void)out_size; (void)ws_size;
  const int*   x    = (const int*)d_in[0];
  const float* emb  = (const float*)d_in[1];
  const float* Wih0 = (const float*)d_in[2];
  const float* Whh0 = (const float*)d_in[3];
  const float* b0   = (const float*)d_in[4];
  const float* Wih1 = (const float*)d_in[5];
  const float* Whh1 = (const float*)d_in[6];
  const float* b1   = (const float*)d_in[7];
  const float* fcW  = (const float*)d_in[8];
  const float* fcb  = (const float*)d_in[9];
  const float* h0in = (const float*)d_in[10];
  const float* c0in = (const float*)d_in[11];
  float* out = (float*)d_out;
  char* ws = (char*)d_ws;

  // workspace layout (bytes, 16B aligned); total ~57.3 MB
  unsigned short* wzh      = (unsigned short*)(ws + 0);           // 25,427,968
  unsigned short* wzl      = (unsigned short*)(ws + 25427968);    // 25,427,968
  float*          embprojT = (float*)(ws + 50855936);             //  2,097,152
  float*          embT     = (float*)(ws + 52953088);             //    524,288
  unsigned short* h0bh     = (unsigned short*)(ws + 53477376);    //    270,336
  unsigned short* h0bl     = (unsigned short*)(ws + 53747712);    //    270,336
  unsigned short* h1bh     = (unsigned short*)(ws + 54018048);    //    270,336
  unsigned short* h1bl     = (unsigned short*)(ws + 54288384);    //    270,336
  float*          c0       = (float*)(ws + 54558720);             //    262,144
  float*          c1       = (float*)(ws + 54820864);             //    262,144
  float*          gx1      = (float*)(ws + 55083008);             //  2,097,152
  int*            xT       = (int*)(ws + 57180160);               //     65,536
  int*            bar      = (int*)(ws + 57245696);               //     32,768

  hipLaunchKernelGGL(init_misc, dim3(512), dim3(256), 0, stream,
                     x, emb, h0in, c0in, xT, embT, h0bh, h0bl, h1bh, h1bl, c0, c1, bar);
  hipLaunchKernelGGL(swizzle_kernel, dim3(6208), dim3(256), 0, stream,
                     Whh0, Wih1, Whh1, fcW, wzh, wzl);
  hipLaunchKernelGGL(embproj_kernel, dim3(256), dim3(256), 0, stream,
                     Wih0, b0, embT, embprojT);

  hipFuncSetAttribute((const void*)scan_kernel,
                      hipFuncAttributeMaxDynamicSharedMemorySize, LDS_BYTES);

  void* args[] = {
    (void*)&wzh, (void*)&wzl, (void*)&embprojT, (void*)&xT,
    (void*)&h0bh, (void*)&h0bl, (void*)&h1bh, (void*)&h1bl,
    (void*)&c0, (void*)&c1, (void*)&gx1, (void*)&b1, (void*)&fcb, (void*)&out,
    (void*)&bar
  };
  hipLaunchCooperativeKernel((void*)scan_kernel, dim3(GRID), dim3(128),
                             args, LDS_BYTES, stream);
}

// Round 8
// 6914.159 us; speedup vs baseline: 1.4187x; 1.2885x over previous
//
#include <hip/hip_runtime.h>

#define HD 1024
#define BB 64
#define TT 256
#define VV 128
#define NSTEPS (TT + 3)
#define KSTR 1056                 // padded k-stride for h buffers (bf16 elems)
#define HS (BB * KSTR)            // one h slot, elems
#define GXS (4 * HD * BB)         // one gx1 slot, floats
#define NBLKW 388                 // worker blocks
#define GRID (NBLKW + 1)          // + 1 barrier-master block
#define GO_OFF 7936               // int offset of 'go' epoch in bar region
#define CHUNK 32768               // ushort elems per block weight chunk (64 KB)
#define LDS_BYTES (65536 + 8192)

typedef __attribute__((ext_vector_type(8))) short bf16x8;
typedef __attribute__((ext_vector_type(4))) float f32x4;
typedef unsigned long long u64;

#define MFMA16(a, b, c) __builtin_amdgcn_mfma_f32_16x16x32_bf16((a), (b), (c), 0, 0, 0)

__device__ __forceinline__ unsigned short f2bf(float f) {
  union { float f; unsigned u; } v; v.f = f;
  unsigned r = v.u + 0x7fffu + ((v.u >> 16) & 1u);
  return (unsigned short)(r >> 16);
}
__device__ __forceinline__ float bf2f(unsigned short h) {
  union { unsigned u; float f; } v; v.u = ((unsigned)h) << 16; return v.f;
}
__device__ __forceinline__ float sigf(float x) { return 1.0f / (1.0f + __expf(-x)); }
__device__ __forceinline__ float tanh_f(float x) { return 1.0f - 2.0f / (__expf(2.0f * x) + 1.0f); }

// ---- LLC-direct (agent-coherent, L1/L2-bypassing) access helpers ----
__device__ __forceinline__ bf16x8 ld_sc16(const unsigned short* p) {
  union { bf16x8 v; u64 q[2]; } u;
  const u64* pp = (const u64*)p;
  u.q[0] = __hip_atomic_load(pp,     __ATOMIC_RELAXED, __HIP_MEMORY_SCOPE_AGENT);
  u.q[1] = __hip_atomic_load(pp + 1, __ATOMIC_RELAXED, __HIP_MEMORY_SCOPE_AGENT);
  return u.v;
}
__device__ __forceinline__ float2 ld_sc8f(const float* p) {
  union { float2 f; u64 q; } u;
  u.q = __hip_atomic_load((const u64*)p, __ATOMIC_RELAXED, __HIP_MEMORY_SCOPE_AGENT);
  return u.f;
}
__device__ __forceinline__ void st_sc8f(float* p, float2 v) {
  union { float2 f; u64 q; } u; u.f = v;
  __hip_atomic_store((u64*)p, u.q, __ATOMIC_RELAXED, __HIP_MEMORY_SCOPE_AGENT);
}
__device__ __forceinline__ void st_sc2(unsigned short* p, unsigned short v) {
  __hip_atomic_store(p, v, __ATOMIC_RELAXED, __HIP_MEMORY_SCOPE_AGENT);
}

// ---------------- init: transposes, hi/lo bf16 initial states, barrier zero ---
__global__ __launch_bounds__(256) void init_misc(
    const int* __restrict__ x, const float* __restrict__ emb,
    const float* __restrict__ h0in, const float* __restrict__ c0in,
    int* __restrict__ xT, float* __restrict__ embT,
    unsigned short* __restrict__ h0bh, unsigned short* __restrict__ h0bl,
    unsigned short* __restrict__ h1bh, unsigned short* __restrict__ h1bl,
    float* __restrict__ c0, float* __restrict__ c1,
    int* __restrict__ bar)
{
  int tid = blockIdx.x * blockDim.x + threadIdx.x;
  int stride = gridDim.x * blockDim.x;
  const int nXT = TT * BB, nE = VV * HD, nS = HD * BB, nB = 8192;
  const int total = nXT + nE + 4 * nS + nB;
  for (int i = tid; i < total; i += stride) {
    int j = i;
    if (j < nXT) { xT[j] = x[(j & 63) * TT + (j >> 6)]; continue; }       // xT[t][b]
    j -= nXT;
    if (j < nE) { embT[j] = emb[(j & 127) * HD + (j >> 7)]; continue; }   // embT[k][v]
    j -= nE;
    if (j < nS) { int b = j >> 10, n = j & 1023;
      float v = h0in[b * HD + n];
      unsigned short hi = f2bf(v);
      h0bh[HS + b * KSTR + n] = hi;
      h0bl[HS + b * KSTR + n] = f2bf(v - bf2f(hi));
      continue; }                                                          // slot 1
    j -= nS;
    if (j < nS) { int b = j >> 10, n = j & 1023;
      float v = h0in[nS + b * HD + n];
      unsigned short hi = f2bf(v);
      h1bh[HS + b * KSTR + n] = hi;
      h1bl[HS + b * KSTR + n] = f2bf(v - bf2f(hi));
      continue; }
    j -= nS;
    if (j < nS) { int n = j >> 6, b = j & 63;
      c0[n * BB + b] = c0in[b * HD + n]; continue; }
    j -= nS;
    if (j < nS) { int n = j >> 6, b = j & 63;
      c1[n * BB + b] = c0in[nS + b * HD + n]; continue; }
    j -= nS;
    bar[j] = 0;
  }
}

// ---------------- emb_proj = emb @ W_ih0^T + b0, stored [row(4096)][v] fp32 ----
__global__ __launch_bounds__(256) void embproj_kernel(
    const float* __restrict__ Wih0, const float* __restrict__ b0,
    const float* __restrict__ embT, float* __restrict__ embprojT)
{
  const int lane = threadIdx.x & 63;
  const int wave = (blockIdx.x * blockDim.x + threadIdx.x) >> 6;  // 0..1023
  const int n0 = __builtin_amdgcn_readfirstlane(wave * 4);
  const float* __restrict__ r0 = Wih0 + (size_t)n0 * HD;
  const float* __restrict__ r1 = r0 + HD;
  const float* __restrict__ r2 = r1 + HD;
  const float* __restrict__ r3 = r2 + HD;
  float a00=0,a01=0,a10=0,a11=0,a20=0,a21=0,a30=0,a31=0;
  #pragma unroll 4
  for (int k = 0; k < HD; ++k) {
    float e0 = embT[k * VV + lane];
    float e1 = embT[k * VV + 64 + lane];
    float w0 = r0[k], w1 = r1[k], w2 = r2[k], w3 = r3[k];
    a00 = fmaf(e0, w0, a00); a01 = fmaf(e1, w0, a01);
    a10 = fmaf(e0, w1, a10); a11 = fmaf(e1, w1, a11);
    a20 = fmaf(e0, w2, a20); a21 = fmaf(e1, w2, a21);
    a30 = fmaf(e0, w3, a30); a31 = fmaf(e1, w3, a31);
  }
  float bb0 = b0[n0], bb1 = b0[n0+1], bb2 = b0[n0+2], bb3 = b0[n0+3];
  embprojT[(n0+0)*VV + lane]      = a00 + bb0;
  embprojT[(n0+0)*VV + 64 + lane] = a01 + bb0;
  embprojT[(n0+1)*VV + lane]      = a10 + bb1;
  embprojT[(n0+1)*VV + 64 + lane] = a11 + bb1;
  embprojT[(n0+2)*VV + lane]      = a20 + bb2;
  embprojT[(n0+2)*VV + 64 + lane] = a21 + bb2;
  embprojT[(n0+3)*VV + lane]      = a30 + bb3;
  embprojT[(n0+3)*VV + 64 + lane] = a31 + bb3;
}

// ---------------- weight swizzle into per-block MFMA A-frag chunks --------
// chunk[blk][mt][kt][lane][j]  (j=0..7 bf16) ; A[m=lane&15][k=(lane>>4)*8+j]
// hi = bf16(w), lo = bf16(w - hi)
__global__ __launch_bounds__(256) void swizzle_kernel(
    const float* __restrict__ Whh0, const float* __restrict__ Wih1,
    const float* __restrict__ Whh1, const float* __restrict__ fcW,
    unsigned short* __restrict__ wzh, unsigned short* __restrict__ wzl)
{
  int W = (blockIdx.x * blockDim.x + threadIdx.x) >> 6;  // wave id 0..24831
  int lane = threadIdx.x & 63;
  int blk = W >> 6, rem = W & 63;
  int mt = rem >> 5, kt = rem & 31;
  int m = lane & 15, q = lane >> 4;
  int rho = mt * 16 + m;
  const float* src; int srow;
  if (blk < 128)      { src = Whh0; srow = (rho >> 3) * HD + blk * 8 + (rho & 7); }
  else if (blk < 256) { src = Wih1; srow = (blk - 128) * 32 + rho; }
  else if (blk < 384) { src = Whh1; srow = (rho >> 3) * HD + (blk - 256) * 8 + (rho & 7); }
  else                { src = fcW;  srow = (blk - 384) * 32 + rho; }
  int k0 = kt * 32 + q * 8;
  const float* sp = src + (size_t)srow * HD + k0;
  uint4 ohi, olo;
  unsigned short* ph = (unsigned short*)&ohi;
  unsigned short* pl = (unsigned short*)&olo;
  #pragma unroll
  for (int j = 0; j < 8; ++j) {
    float wv = sp[j];
    unsigned short hi = f2bf(wv);
    ph[j] = hi;
    pl[j] = f2bf(wv - bf2f(hi));
  }
  size_t off = (size_t)blk * CHUNK + ((size_t)(mt * 32 + kt) * 64 + lane) * 8;
  *(uint4*)(wzh + off) = ohi;
  *(uint4*)(wzl + off) = olo;
}

// ---------------- persistent pipelined MFMA scan (3-term split precision) ----
// Whi in LDS; Wlo plain L2-cached loads (L2 now stays warm: NO agent fences);
// mutable cross-block data (h hi/lo, gx1) via LLC-direct relaxed atomics;
// c-state in VGPRs; master-block flag barrier; fence-free.
__global__ __launch_bounds__(128, 2) void scan_kernel(
    const unsigned short* __restrict__ wzh,
    const unsigned short* __restrict__ wzl,
    const float* __restrict__ embprojT,
    const int* __restrict__ xT,
    unsigned short* __restrict__ h0bh, unsigned short* __restrict__ h0bl,
    unsigned short* __restrict__ h1bh, unsigned short* __restrict__ h1bl,
    float* __restrict__ c0,
    float* __restrict__ c1,
    float* __restrict__ gx1,
    const float* __restrict__ b1v,
    const float* __restrict__ fcb,
    float* __restrict__ out,
    int* __restrict__ bar)
{
  extern __shared__ char smem[];
  const bf16x8* wfrag = (const bf16x8*)smem;       // 4096 frags = 64 KB (hi)
  float* red = (float*)(smem + 65536);             // 2048 floats = 8 KB

  const int tid = threadIdx.x, lane = tid & 63, w = tid >> 6;
  const int blk = blockIdx.x;

  // ---------- barrier master block ----------
  if (blk == NBLKW) {
    const int f0 = tid, f1 = tid + 128, f2 = tid + 256;
    for (int s = 1; s <= NSTEPS; ++s) {
      while (__hip_atomic_load(&bar[f0 * 16], __ATOMIC_RELAXED, __HIP_MEMORY_SCOPE_AGENT) < s)
        __builtin_amdgcn_s_sleep(1);
      while (__hip_atomic_load(&bar[f1 * 16], __ATOMIC_RELAXED, __HIP_MEMORY_SCOPE_AGENT) < s)
        __builtin_amdgcn_s_sleep(1);
      while (__hip_atomic_load(&bar[f2 * 16], __ATOMIC_RELAXED, __HIP_MEMORY_SCOPE_AGENT) < s)
        __builtin_amdgcn_s_sleep(1);
      if (tid < 4)
        while (__hip_atomic_load(&bar[(384 + tid) * 16], __ATOMIC_RELAXED, __HIP_MEMORY_SCOPE_AGENT) < s)
          __builtin_amdgcn_s_sleep(1);
      __syncthreads();
      if (tid == 0) {
        asm volatile("" ::: "memory");
        __hip_atomic_store(&bar[GO_OFF], s, __ATOMIC_RELAXED, __HIP_MEMORY_SCOPE_AGENT);
      }
    }
    return;
  }

  const int kt0 = w * 16;

  // one-time: block's hi weight chunk -> LDS
  {
    const uint4* srcp = (const uint4*)(wzh + (size_t)blk * CHUNK);
    uint4* dst = (uint4*)smem;
    for (int i = tid; i < 4096; i += 128) dst[i] = srcp[i];
  }
  __syncthreads();
  const unsigned short* wlo = wzl + (size_t)blk * CHUNK;   // lo chunk: L2-resident

  int part, n0 = 0, rg0 = 0;
  if (blk < 128)      { part = 0; n0 = blk * 8; }
  else if (blk < 256) { part = 1; rg0 = (blk - 128) * 32; }
  else if (blk < 384) { part = 2; n0 = (blk - 256) * 8; }
  else                { part = 3; rg0 = (blk - 384) * 32; }

  // c-state in VGPRs: thread owns (n = n0 + (tid>>4), b = ro*32 + (tid&15)*2 + {0,1})
  float creg[2][2];
  if (part == 0 || part == 2) {
    const float* cc = (part == 0) ? c0 : c1;
    int nl = tid >> 4, bp = (tid & 15) * 2;
    int n = n0 + nl;
    float2 v0 = *(const float2*)&cc[n * BB + bp];
    float2 v1 = *(const float2*)&cc[n * BB + 32 + bp];
    creg[0][0] = v0.x; creg[0][1] = v0.y;
    creg[1][0] = v1.x; creg[1][1] = v1.y;
  }

  // per-nt gather offsets into h buffers (elems)
  int goff0 = (0 * 16 + (lane & 15)) * KSTR + (lane >> 4) * 8;
  int goff1 = (1 * 16 + (lane & 15)) * KSTR + (lane >> 4) * 8;
  int goff2 = (2 * 16 + (lane & 15)) * KSTR + (lane >> 4) * 8;
  int goff3 = (3 * 16 + (lane & 15)) * KSTR + (lane >> 4) * 8;

  for (int s = 0; s < NSTEPS; ++s) {
    bool active = (part == 0) ? (s < TT)
                : (part == 1) ? (s >= 1 && s <= TT)
                : (part == 2) ? (s >= 2 && s <= TT + 1)
                :               (s >= 3);
    if (active) {
      const int ps = (s + 1) & 1, cs2 = s & 1;
      const bool l0src = (part == 0 || part == 1);
      const unsigned short* hsrcH = (l0src ? h0bh : h1bh) + ps * HS;
      const unsigned short* hsrcL = (l0src ? h0bl : h1bl) + ps * HS;
      const unsigned short* hbh0 = hsrcH + goff0;
      const unsigned short* hbh1 = hsrcH + goff1;
      const unsigned short* hbh2 = hsrcH + goff2;
      const unsigned short* hbh3 = hsrcH + goff3;
      const unsigned short* hbl0 = hsrcL + goff0;
      const unsigned short* hbl1 = hsrcL + goff1;
      const unsigned short* hbl2 = hsrcL + goff2;
      const unsigned short* hbl3 = hsrcL + goff3;

      f32x4 acc[2][4];
      #pragma unroll
      for (int i = 0; i < 2; ++i)
        #pragma unroll
        for (int j = 0; j < 4; ++j) acc[i][j] = (f32x4){0.f, 0.f, 0.f, 0.f};

      #pragma unroll 4
      for (int kk = 0; kk < 16; ++kk) {
        int kt = kt0 + kk;
        bf16x8 a0  = wfrag[kt * 64 + lane];
        bf16x8 a1  = wfrag[(32 + kt) * 64 + lane];
        bf16x8 a0l = *(const bf16x8*)(wlo + ((size_t)(0 * 32 + kt) * 64 + lane) * 8);
        bf16x8 a1l = *(const bf16x8*)(wlo + ((size_t)(1 * 32 + kt) * 64 + lane) * 8);
        bf16x8 b0  = ld_sc16(hbh0 + kt * 32);
        bf16x8 b1  = ld_sc16(hbh1 + kt * 32);
        bf16x8 b2  = ld_sc16(hbh2 + kt * 32);
        bf16x8 b3  = ld_sc16(hbh3 + kt * 32);
        bf16x8 c0f = ld_sc16(hbl0 + kt * 32);
        bf16x8 c1f = ld_sc16(hbl1 + kt * 32);
        bf16x8 c2f = ld_sc16(hbl2 + kt * 32);
        bf16x8 c3f = ld_sc16(hbl3 + kt * 32);
        // hi*hi
        acc[0][0] = MFMA16(a0, b0, acc[0][0]);
        acc[0][1] = MFMA16(a0, b1, acc[0][1]);
        acc[0][2] = MFMA16(a0, b2, acc[0][2]);
        acc[0][3] = MFMA16(a0, b3, acc[0][3]);
        acc[1][0] = MFMA16(a1, b0, acc[1][0]);
        acc[1][1] = MFMA16(a1, b1, acc[1][1]);
        acc[1][2] = MFMA16(a1, b2, acc[1][2]);
        acc[1][3] = MFMA16(a1, b3, acc[1][3]);
        // hi*lo (h-lo)
        acc[0][0] = MFMA16(a0, c0f, acc[0][0]);
        acc[0][1] = MFMA16(a0, c1f, acc[0][1]);
        acc[0][2] = MFMA16(a0, c2f, acc[0][2]);
        acc[0][3] = MFMA16(a0, c3f, acc[0][3]);
        acc[1][0] = MFMA16(a1, c0f, acc[1][0]);
        acc[1][1] = MFMA16(a1, c1f, acc[1][1]);
        acc[1][2] = MFMA16(a1, c2f, acc[1][2]);
        acc[1][3] = MFMA16(a1, c3f, acc[1][3]);
        // lo*hi (w-lo)
        acc[0][0] = MFMA16(a0l, b0, acc[0][0]);
        acc[0][1] = MFMA16(a0l, b1, acc[0][1]);
        acc[0][2] = MFMA16(a0l, b2, acc[0][2]);
        acc[0][3] = MFMA16(a0l, b3, acc[0][3]);
        acc[1][0] = MFMA16(a1l, b0, acc[1][0]);
        acc[1][1] = MFMA16(a1l, b1, acc[1][1]);
        acc[1][2] = MFMA16(a1l, b2, acc[1][2]);
        acc[1][3] = MFMA16(a1l, b3, acc[1][3]);
      }

      // epilogue: 2 rounds (b 0..31, 32..63); K-partials reduced in LDS
      #pragma unroll
      for (int ro = 0; ro < 2; ++ro) {
        #pragma unroll
        for (int mt = 0; mt < 2; ++mt)
          #pragma unroll
          for (int ntl = 0; ntl < 2; ++ntl) {
            f32x4 v = acc[mt][ro * 2 + ntl];
            int base = w * 1024 + (mt * 16 + (lane >> 4) * 4) * 32 + ntl * 16 + (lane & 15);
            red[base + 0 * 32] = v[0];
            red[base + 1 * 32] = v[1];
            red[base + 2 * 32] = v[2];
            red[base + 3 * 32] = v[3];
          }
        __syncthreads();

        if (part == 0 || part == 2) {
          int nl = tid >> 4, bp = (tid & 15) * 2;
          int b = ro * 32 + bp;
          int n = n0 + nl;
          float2 p0, p1, p2, p3;
          {
            int ix = (0 * 8 + nl) * 32 + bp;
            float2 u0 = *(const float2*)&red[ix], u1 = *(const float2*)&red[1024 + ix];
            p0 = make_float2(u0.x + u1.x, u0.y + u1.y);
            ix = (1 * 8 + nl) * 32 + bp;
            u0 = *(const float2*)&red[ix]; u1 = *(const float2*)&red[1024 + ix];
            p1 = make_float2(u0.x + u1.x, u0.y + u1.y);
            ix = (2 * 8 + nl) * 32 + bp;
            u0 = *(const float2*)&red[ix]; u1 = *(const float2*)&red[1024 + ix];
            p2 = make_float2(u0.x + u1.x, u0.y + u1.y);
            ix = (3 * 8 + nl) * 32 + bp;
            u0 = *(const float2*)&red[ix]; u1 = *(const float2*)&red[1024 + ix];
            p3 = make_float2(u0.x + u1.x, u0.y + u1.y);
          }
          float pi0, pf0, pg0, po0, pi1, pf1, pg1, po1;
          if (part == 0) {
            int xv0 = xT[s * BB + b], xv1 = xT[s * BB + b + 1];
            pi0 = p0.x + embprojT[(0 * HD + n) * VV + xv0];
            pf0 = p1.x + embprojT[(1 * HD + n) * VV + xv0];
            pg0 = p2.x + embprojT[(2 * HD + n) * VV + xv0];
            po0 = p3.x + embprojT[(3 * HD + n) * VV + xv0];
            pi1 = p0.y + embprojT[(0 * HD + n) * VV + xv1];
            pf1 = p1.y + embprojT[(1 * HD + n) * VV + xv1];
            pg1 = p2.y + embprojT[(2 * HD + n) * VV + xv1];
            po1 = p3.y + embprojT[(3 * HD + n) * VV + xv1];
          } else {
            const float* gx = gx1 + ps * GXS;
            float2 q0 = ld_sc8f(&gx[(0 * HD + n) * BB + b]);
            float2 q1 = ld_sc8f(&gx[(1 * HD + n) * BB + b]);
            float2 q2 = ld_sc8f(&gx[(2 * HD + n) * BB + b]);
            float2 q3 = ld_sc8f(&gx[(3 * HD + n) * BB + b]);
            pi0 = p0.x + q0.x; pf0 = p1.x + q1.x; pg0 = p2.x + q2.x; po0 = p3.x + q3.x;
            pi1 = p0.y + q0.y; pf1 = p1.y + q1.y; pg1 = p2.y + q2.y; po1 = p3.y + q3.y;
          }
          float cn0 = sigf(pf0) * creg[ro][0] + sigf(pi0) * tanh_f(pg0);
          float cn1 = sigf(pf1) * creg[ro][1] + sigf(pi1) * tanh_f(pg1);
          creg[ro][0] = cn0; creg[ro][1] = cn1;
          float hv0 = sigf(po0) * tanh_f(cn0);
          float hv1 = sigf(po1) * tanh_f(cn1);
          unsigned short* hwh = ((part == 0) ? h0bh : h1bh) + cs2 * HS;
          unsigned short* hwl = ((part == 0) ? h0bl : h1bl) + cs2 * HS;
          unsigned short e0 = f2bf(hv0);
          unsigned short e1 = f2bf(hv1);
          st_sc2(&hwh[b * KSTR + n],       e0);
          st_sc2(&hwh[(b + 1) * KSTR + n], e1);
          st_sc2(&hwl[b * KSTR + n],       f2bf(hv0 - bf2f(e0)));
          st_sc2(&hwl[(b + 1) * KSTR + n], f2bf(hv1 - bf2f(e1)));
        } else {
          int rb = (tid >> 4) * 4, bp = (tid & 15) * 2;
          int b = ro * 32 + bp;
          #pragma unroll
          for (int rr = 0; rr < 4; ++rr) {
            int rho = rb + rr, ix = rho * 32 + bp;
            float2 u0 = *(const float2*)&red[ix], u1 = *(const float2*)&red[1024 + ix];
            if (part == 1) {
              float bias = b1v[rg0 + rho];
              float2 sm = make_float2(u0.x + u1.x + bias, u0.y + u1.y + bias);
              st_sc8f(&gx1[cs2 * GXS + (rg0 + rho) * BB + b], sm);
            } else {
              float bias = fcb[rg0 + rho];
              int t = s - 3;
              out[(size_t)b * (TT * VV) + t * VV + rg0 + rho]       = u0.x + u1.x + bias;
              out[(size_t)(b + 1) * (TT * VV) + t * VV + rg0 + rho] = u0.y + u1.y + bias;
            }
          }
        }
        __syncthreads();
      }
    }

    // ---------- fence-free flag barrier ----------
    // Write-through (sc) stores complete at LLC when vmcnt drains; every wave
    // drains before s_barrier, so tid0's flag publishes after all block data.
    __builtin_amdgcn_s_waitcnt(0);
    __syncthreads();
    if (tid == 0) {
      __hip_atomic_store(&bar[blk * 16], s + 1, __ATOMIC_RELAXED, __HIP_MEMORY_SCOPE_AGENT);
      while (__hip_atomic_load(&bar[GO_OFF], __ATOMIC_RELAXED, __HIP_MEMORY_SCOPE_AGENT) < s + 1)
        __builtin_amdgcn_s_sleep(1);
    }
    __syncthreads();
    asm volatile("" ::: "memory");   // compiler barrier: no hoisting of next-step sc loads
  }
}

extern "C" void kernel_launch(void* const* d_in, const int* in_sizes, int n_in,
                              void* d_out, int out_size, void* d_ws, size_t ws_size,
                              hipStream_t stream) {
  (void)in_sizes; (void)n_in; (void)out_size; (void)ws_size;
  const int*   x    = (const int*)d_in[0];
  const float* emb  = (const float*)d_in[1];
  const float* Wih0 = (const float*)d_in[2];
  const float* Whh0 = (const float*)d_in[3];
  const float* b0   = (const float*)d_in[4];
  const float* Wih1 = (const float*)d_in[5];
  const float* Whh1 = (const float*)d_in[6];
  const float* b1   = (const float*)d_in[7];
  const float* fcW  = (const float*)d_in[8];
  const float* fcb  = (const float*)d_in[9];
  const float* h0in = (const float*)d_in[10];
  const float* c0in = (const float*)d_in[11];
  float* out = (float*)d_out;
  char* ws = (char*)d_ws;

  // workspace layout (bytes, 16B aligned); total ~57.3 MB
  unsigned short* wzh      = (unsigned short*)(ws + 0);           // 25,427,968
  unsigned short* wzl      = (unsigned short*)(ws + 25427968);    // 25,427,968
  float*          embprojT = (float*)(ws + 50855936);             //  2,097,152
  float*          embT     = (float*)(ws + 52953088);             //    524,288
  unsigned short* h0bh     = (unsigned short*)(ws + 53477376);    //    270,336
  unsigned short* h0bl     = (unsigned short*)(ws + 53747712);    //    270,336
  unsigned short* h1bh     = (unsigned short*)(ws + 54018048);    //    270,336
  unsigned short* h1bl     = (unsigned short*)(ws + 54288384);    //    270,336
  float*          c0       = (float*)(ws + 54558720);             //    262,144
  float*          c1       = (float*)(ws + 54820864);             //    262,144
  float*          gx1      = (float*)(ws + 55083008);             //  2,097,152
  int*            xT       = (int*)(ws + 57180160);               //     65,536
  int*            bar      = (int*)(ws + 57245696);               //     32,768

  hipLaunchKernelGGL(init_misc, dim3(512), dim3(256), 0, stream,
                     x, emb, h0in, c0in, xT, embT, h0bh, h0bl, h1bh, h1bl, c0, c1, bar);
  hipLaunchKernelGGL(swizzle_kernel, dim3(6208), dim3(256), 0, stream,
                     Whh0, Wih1, Whh1, fcW, wzh, wzl);
  hipLaunchKernelGGL(embproj_kernel, dim3(256), dim3(256), 0, stream,
                     Wih0, b0, embT, embprojT);

  hipFuncSetAttribute((const void*)scan_kernel,
                      hipFuncAttributeMaxDynamicSharedMemorySize, LDS_BYTES);

  void* args[] = {
    (void*)&wzh, (void*)&wzl, (void*)&embprojT, (void*)&xT,
    (void*)&h0bh, (void*)&h0bl, (void*)&h1bh, (void*)&h1bl,
    (void*)&c0, (void*)&c1, (void*)&gx1, (void*)&b1, (void*)&fcb, (void*)&out,
    (void*)&bar
  };
  hipLaunchCooperativeKernel((void*)scan_kernel, dim3(GRID), dim3(128),
                             args, LDS_BYTES, stream);
}